// Round 4
// baseline (620.639 us; speedup 1.0000x reference)
//
#include <hip/hip_runtime.h>
#include <hip/hip_bf16.h>

typedef __hip_bfloat16 bf16;
typedef unsigned short u16;
typedef unsigned int u32;
typedef __attribute__((ext_vector_type(8))) short short8;
typedef __attribute__((ext_vector_type(4))) float f32x4;

static constexpr float AVG_LOG_C = 2.8332133440562162f; // ln(17)
#define BCAP 4096   // staging capacity per 128-node bucket (avg 2046, P(overflow)~0)

__device__ __forceinline__ u32 f2bf_bits(float f) {
    u32 u = __float_as_uint(f);
    return (u + 0x7fffu + ((u >> 16) & 1u)) >> 16;   // RNE to bf16 bits
}
__device__ __forceinline__ float bf2f(u16 b) {
    return __uint_as_float(((u32)b) << 16);
}

// ---------------------------------------------------------------- detect + zero bucket counters
__global__ __launch_bounds__(1024) void detect_zero_kernel(
    const u32* __restrict__ xwords, int* __restrict__ flag,
    int* __restrict__ bcnt, int nb) {
    if (blockIdx.x == 0) {
        int tid = threadIdx.x;
        if (tid < 64) {
            int good = 0;
            for (int i = tid; i < 2048; i += 64) {
                u32 lo = xwords[i] & 0xffffu;
                float v = __uint_as_float(lo << 16);
                float a = fabsf(v);
                if (v == 0.0f || (a >= 1e-3f && a <= 100.0f)) good++;
            }
            for (int off = 32; off; off >>= 1) good += __shfl_xor(good, off, 64);
            if (tid == 0) *flag = (2 * good > 2048) ? 1 : 0;
        }
    } else {
        int i = (blockIdx.x - 1) * 1024 + threadIdx.x;
        if (i < nb) bcnt[i] = 0;
    }
}

// ---------------------------------------------------------------- convert weights to f32 masters
struct CvtTab {
    const void* src[16];
    float* dst[16];
    int n[16];
    int total;
};

__global__ void convert_kernel(CvtTab t, const int* __restrict__ flag) {
    int i = blockIdx.x * 256 + threadIdx.x;
    if (i >= t.total) return;
    int k = 0;
    while (i >= t.n[k]) { i -= t.n[k]; ++k; }
    float v;
    if (*flag)
        v = __bfloat162float(((const bf16*)t.src[k])[i]);
    else
        v = ((const float*)t.src[k])[i];
    t.dst[k][i] = v;
}

// ---------------------------------------------------------------- bucketed CSR build
// pass 1: append (dstlow<<17 | src) into per-bucket staging
__global__ void bucket_scatter_kernel(
    const int* __restrict__ srcs, const int* __restrict__ dsts,
    int* __restrict__ bcnt, u32* __restrict__ bstage, int e) {
    int i = blockIdx.x * 256 + threadIdx.x;
    if (i < e) {
        int d = dsts[i];
        int b = d >> 7;
        int pos = atomicAdd(&bcnt[b], 1);
        if (pos < BCAP)
            bstage[(size_t)b * BCAP + pos] = (u32)srcs[i] | ((u32)(d & 127) << 17);
    }
}

// pass 2a: exclusive scan of bucket sizes (nb <= 1024, single block)
__global__ __launch_bounds__(1024) void bucket_scan_kernel(
    const int* __restrict__ bcnt, int* __restrict__ bbase, int nb) {
    __shared__ int wsum[16];
    int tid = threadIdx.x, lane = tid & 63, wave = tid >> 6;
    int v = (tid < nb) ? min(bcnt[tid], BCAP) : 0;
    int s = v;
    for (int off = 1; off < 64; off <<= 1) {
        int t = __shfl_up(s, (unsigned)off, 64);
        if (lane >= off) s += t;
    }
    if (lane == 63) wsum[wave] = s;
    __syncthreads();
    if (wave == 0 && lane < 16) {
        int w = wsum[lane];
        for (int off = 1; off < 16; off <<= 1) {
            int t = __shfl_up(w, (unsigned)off, 64);
            if (lane >= off) w += t;
        }
        wsum[lane] = w;
    }
    __syncthreads();
    int incl = s + (wave ? wsum[wave - 1] : 0);
    if (tid < nb) bbase[tid] = incl - v;
    if (tid == nb - 1) bbase[nb] = incl;
}

// pass 2b: per-bucket local sort -> rowptr + elist
__global__ __launch_bounds__(256) void bucket_build_kernel(
    const u32* __restrict__ bstage, const int* __restrict__ bcnt,
    const int* __restrict__ bbase, int* __restrict__ rowptr,
    int* __restrict__ elist, int nb, int n) {
    __shared__ int hist[128];
    __shared__ int hoff[128];
    int b = blockIdx.x, tid = threadIdx.x;
    int cb = min(bcnt[b], BCAP);
    int base = bbase[b];
    if (tid < 128) hist[tid] = 0;
    __syncthreads();
    const u32* st = bstage + (size_t)b * BCAP;
    for (int i = tid; i < cb; i += 256) atomicAdd(&hist[st[i] >> 17], 1);
    __syncthreads();
    if (tid == 0) {
        int run = 0;
        for (int j = 0; j < 128; ++j) { hoff[j] = run; run += hist[j]; }
    }
    __syncthreads();
    if (tid < 128) {
        int node = b * 128 + tid;
        if (node < n) rowptr[node] = base + hoff[tid];
        hist[tid] = hoff[tid];   // becomes cursor
    }
    if (b == 0 && tid == 254) rowptr[n] = bbase[nb];
    __syncthreads();
    for (int i = tid; i < cb; i += 256) {
        u32 e = st[i];
        int pos = atomicAdd(&hist[e >> 17], 1);
        elist[base + pos] = (int)(e & 0x1ffffu);
    }
}

// ---------------------------------------------------------------- fuse postW@linW (f32 out)
__global__ void fuse_w_kernel(
    const float* __restrict__ postW1, const float* __restrict__ postb1,
    const float* __restrict__ linW1, const float* __restrict__ linb1,
    const float* __restrict__ postW2, const float* __restrict__ postb2,
    const float* __restrict__ linW2, const float* __restrict__ linb2,
    float* __restrict__ Wf1, float* __restrict__ bfo1,
    float* __restrict__ Wf2, float* __restrict__ bfo2) {
    const float* postW = blockIdx.y ? postW2 : postW1;
    const float* postb = blockIdx.y ? postb2 : postb1;
    const float* linW  = blockIdx.y ? linW2  : linW1;
    const float* linb  = blockIdx.y ? linb2  : linb1;
    float* Wf          = blockIdx.y ? Wf2 : Wf1;
    float* bfo         = blockIdx.y ? bfo2 : bfo1;

    int idx = blockIdx.x * 256 + threadIdx.x;
    if (idx < 320 * 64) {
        int p = idx >> 6, c = idx & 63;
        float a = 0.f;
        for (int k = 0; k < 64; ++k)
            a = fmaf(postW[p * 64 + k], linW[k * 64 + c], a);
        Wf[idx] = a;
    }
    if (idx < 64) {
        float a = linb[idx];
        for (int k = 0; k < 64; ++k) a = fmaf(postb[k], linW[k * 64 + idx], a);
        bfo[idx] = a;
    }
}

// ---------------------------------------------------------------- pack weights into MFMA B-fragment order
// dst[idx], idx = (((s*NC/16 + c)*64 + lane)*8 + j)
// mode 0: src row-major [K, NC]: src[kk*NC + col]
// mode 1: src pre_W [128,64], logical Wcat[64,128]:
//         col<64 -> src[kk*64+col], col>=64 -> src[(64+kk)*64 + (col-64)]
struct PackTab {
    const float* src[5];
    u16* dst[5];
    int NC[5];
    int sz[5];
    int mode[5];
    int total;
};

__global__ void pack_kernel(PackTab t) {
    int idx = blockIdx.x * 256 + threadIdx.x;
    if (idx >= t.total) return;
    int k = 0;
    while (idx >= t.sz[k]) { idx -= t.sz[k]; ++k; }
    int NC = t.NC[k];
    int nc16 = NC >> 4;
    int j = idx & 7, l = (idx >> 3) & 63;
    int tt = idx >> 9;
    int c = tt % nc16, s = tt / nc16;
    int kk = s * 32 + (l >> 4) * 8 + j;
    int col = c * 16 + (l & 15);
    float v;
    if (t.mode[k] == 0) {
        v = t.src[k][kk * NC + col];
    } else {
        v = (col < 64) ? t.src[k][kk * 64 + col]
                       : t.src[k][(64 + kk) * 64 + (col - 64)];
    }
    t.dst[k][idx] = (u16)f2bf_bits(v);
}

// ---------------------------------------------------------------- generic MFMA GEMM (x->h, h->PQ)
template<int K, int NCOL, int ACT, bool XMODE>   // ACT 0=none 1=lrelu
__global__ __launch_bounds__(256) void mfma_gemm_kernel(
    const void* __restrict__ Araw, const u16* __restrict__ Bfrag,
    const float* __restrict__ bias, u16* __restrict__ out,
    const int* __restrict__ flag, int n) {
    constexpr int S = K / 32, C = NCOL / 16;
    int wave = __builtin_amdgcn_readfirstlane(threadIdx.x >> 6);
    int lane = threadIdx.x & 63;
    int rowbase = blockIdx.x * 64 + wave * 16;
    int arow = rowbase + (lane & 15);
    if (arow >= n) arow = n - 1;
    int koff = (lane >> 4) * 8;
    f32x4 acc[C];
#pragma unroll
    for (int c = 0; c < C; ++c) acc[c] = f32x4{0.f, 0.f, 0.f, 0.f};

    bool isbf = true;
    if constexpr (XMODE) isbf = (*flag != 0);

#pragma unroll
    for (int s = 0; s < S; ++s) {
        short8 a;
        if (isbf) {
            a = *(const short8*)((const u16*)Araw + (size_t)arow * K + s * 32 + koff);
        } else {
            const float* xf = (const float*)Araw + (size_t)arow * K + s * 32 + koff;
            f32x4 x0 = *(const f32x4*)xf;
            f32x4 x1 = *(const f32x4*)(xf + 4);
#pragma unroll
            for (int j = 0; j < 4; ++j) {
                a[j]     = (short)f2bf_bits(x0[j]);
                a[4 + j] = (short)f2bf_bits(x1[j]);
            }
        }
#pragma unroll
        for (int c = 0; c < C; ++c) {
            short8 b = *(const short8*)(Bfrag + ((size_t)(s * C + c) * 64 + lane) * 8);
            acc[c] = __builtin_amdgcn_mfma_f32_16x16x32_bf16(a, b, acc[c], 0, 0, 0);
        }
    }
    int r0 = rowbase + (lane >> 4) * 4;
#pragma unroll
    for (int c = 0; c < C; ++c) {
        int col = c * 16 + (lane & 15);
        float bv = (ACT == 0) ? 0.f : bias[col];
#pragma unroll
        for (int r = 0; r < 4; ++r) {
            int row = r0 + r;
            if (row < n) {
                float v = acc[c][r] + bv;
                if (ACT == 1) v = v > 0.f ? v : 0.2f * v;
                out[(size_t)row * NCOL + col] = (u16)f2bf_bits(v);
            }
        }
    }
}

// ---------------------------------------------------------------- fused aggregation + post-GEMM
// gather Q rows per node -> v-tile in LDS (64 rows x 320, padded to 328) -> MFMA 320->64.
// FINAL=0: hout = relu(.)    FINAL=1: out = relu(.) @ W2 + b2 (epilogue reduction)
template<int FINAL>
__global__ __launch_bounds__(256) void agg_gemm_kernel(
    const u16* __restrict__ PQ, const u16* __restrict__ h,
    const int* __restrict__ rowptr, const int* __restrict__ elist,
    const float* __restrict__ preb, const u16* __restrict__ Bfrag,
    const float* __restrict__ bias, u16* __restrict__ hout,
    const float* __restrict__ W2, const float* __restrict__ b2,
    void* __restrict__ out, const int* __restrict__ flag, int n) {
    constexpr int PAD = 328;                 // u16; 656 B rows, 16B-aligned, bank-skewed
    __shared__ u16 vsh[64 * PAD];            // 41 KB
    int wave = __builtin_amdgcn_readfirstlane(threadIdx.x >> 6);
    int lane = threadIdx.x & 63;
    float pbl = preb[lane];
    int blockbase = blockIdx.x * 64;

    for (int t = 0; t < 16; ++t) {
        int nl = wave * 16 + t;
        int node = blockbase + nl;
        u16* vrow = &vsh[nl * PAD];
        if (node < n) {
            int beg = rowptr[node], end = rowptr[node + 1];
            int cnt = end - beg;
            float s = 0.f, m = -3.4e38f;
            int e = beg;
            for (; e + 4 <= end; e += 4) {
                int s0 = elist[e], s1 = elist[e + 1], s2 = elist[e + 2], s3 = elist[e + 3];
                float q0 = bf2f(PQ[(size_t)s0 * 128 + 64 + lane]);
                float q1 = bf2f(PQ[(size_t)s1 * 128 + 64 + lane]);
                float q2 = bf2f(PQ[(size_t)s2 * 128 + 64 + lane]);
                float q3 = bf2f(PQ[(size_t)s3 * 128 + 64 + lane]);
                s += (q0 + q1) + (q2 + q3);
                m = fmaxf(fmaxf(m, fmaxf(q0, q1)), fmaxf(q2, q3));
            }
            for (; e < end; ++e) {
                float q = bf2f(PQ[(size_t)elist[e] * 128 + 64 + lane]);
                s += q;
                m = fmaxf(m, q);
            }
            float mean, mx, deg;
            if (cnt > 0) {
                deg = (float)cnt;
                float p = bf2f(PQ[(size_t)node * 128 + lane]) + pbl;
                mean = p + s / deg;
                mx = p + m;
            } else {
                deg = 1.f; mean = 0.f; mx = 0.f;
            }
            float att = AVG_LOG_C / logf(deg + 1.f);
            float lin = deg * (1.f / 16.f);
            vrow[lane]       = h[(size_t)node * 64 + lane];
            vrow[64 + lane]  = (u16)f2bf_bits(att * mean);
            vrow[128 + lane] = (u16)f2bf_bits(att * mx);
            vrow[192 + lane] = (u16)f2bf_bits(lin * mean);
            vrow[256 + lane] = (u16)f2bf_bits(lin * mx);
        } else {
            vrow[lane] = 0; vrow[64 + lane] = 0; vrow[128 + lane] = 0;
            vrow[192 + lane] = 0; vrow[256 + lane] = 0;
        }
    }
    __syncthreads();

    // GEMM: A from LDS, K=320 (S=10), NCOL=64 (C=4)
    int arl = wave * 16 + (lane & 15);
    int koff = (lane >> 4) * 8;
    f32x4 acc[4];
#pragma unroll
    for (int c = 0; c < 4; ++c) acc[c] = f32x4{0.f, 0.f, 0.f, 0.f};
#pragma unroll
    for (int s = 0; s < 10; ++s) {
        short8 a = *(const short8*)(&vsh[arl * PAD + s * 32 + koff]);
#pragma unroll
        for (int c = 0; c < 4; ++c) {
            short8 b = *(const short8*)(Bfrag + ((size_t)(s * 4 + c) * 64 + lane) * 8);
            acc[c] = __builtin_amdgcn_mfma_f32_16x16x32_bf16(a, b, acc[c], 0, 0, 0);
        }
    }
    int r0 = blockbase + wave * 16 + (lane >> 4) * 4;
    if constexpr (!FINAL) {
#pragma unroll
        for (int c = 0; c < 4; ++c) {
            int col = c * 16 + (lane & 15);
            float bv = bias[col];
#pragma unroll
            for (int r = 0; r < 4; ++r) {
                int row = r0 + r;
                if (row < n)
                    hout[(size_t)row * 64 + col] = (u16)f2bf_bits(fmaxf(acc[c][r] + bv, 0.f));
            }
        }
    } else {
        float part[4] = {0.f, 0.f, 0.f, 0.f};
#pragma unroll
        for (int c = 0; c < 4; ++c) {
            int col = c * 16 + (lane & 15);
            float bv = bias[col];
            float w2 = W2[col];
#pragma unroll
            for (int r = 0; r < 4; ++r)
                part[r] = fmaf(fmaxf(acc[c][r] + bv, 0.f), w2, part[r]);
        }
#pragma unroll
        for (int r = 0; r < 4; ++r) {
            float v = part[r];
            v += __shfl_xor(v, 1, 64);
            v += __shfl_xor(v, 2, 64);
            v += __shfl_xor(v, 4, 64);
            v += __shfl_xor(v, 8, 64);
            if ((lane & 15) == 0) {
                int row = r0 + r;
                if (row < n) {
                    float res = v + b2[0];
                    if (*flag) ((u16*)out)[row] = (u16)f2bf_bits(res);
                    else       ((float*)out)[row] = res;
                }
            }
        }
    }
}

// ---------------------------------------------------------------- launch
extern "C" void kernel_launch(void* const* d_in, const int* in_sizes, int n_in,
                              void* d_out, int out_size, void* d_ws, size_t ws_size,
                              hipStream_t stream) {
    const int N = in_sizes[0] / 128;
    const int E = in_sizes[2] / 2;
    const int nb = (N + 127) >> 7;
    const int* ei = (const int*)d_in[2];
    const int* esrc = ei;
    const int* edst = ei + E;

    char* w = (char*)d_ws;
    auto alloc = [&](size_t bytes) -> void* {
        void* p = (void*)w;
        w += (bytes + 255) & ~(size_t)255;
        return p;
    };
    int* flag    = (int*)alloc(4);
    int* bcnt    = (int*)alloc((size_t)nb * 4);
    int* bbase   = (int*)alloc((size_t)(nb + 1) * 4);
    u32* bstage  = (u32*)alloc((size_t)nb * BCAP * 4);
    int* rowptr  = (int*)alloc((size_t)(N + 1) * 4);
    int* elist   = (int*)alloc((size_t)E * 4);
    // f32 masters
    float* W0f   = (float*)alloc(128 * 64 * 4);
    float* b0f   = (float*)alloc(64 * 4);
    float* pre1  = (float*)alloc(128 * 64 * 4);
    float* preb1 = (float*)alloc(64 * 4);
    float* post1 = (float*)alloc(320 * 64 * 4);
    float* postb1= (float*)alloc(64 * 4);
    float* lin1  = (float*)alloc(64 * 64 * 4);
    float* linb1 = (float*)alloc(64 * 4);
    float* pre2  = (float*)alloc(128 * 64 * 4);
    float* preb2 = (float*)alloc(64 * 4);
    float* post2 = (float*)alloc(320 * 64 * 4);
    float* postb2= (float*)alloc(64 * 4);
    float* lin2  = (float*)alloc(64 * 64 * 4);
    float* linb2 = (float*)alloc(64 * 4);
    float* W2f   = (float*)alloc(64 * 4);
    float* b2f_  = (float*)alloc(4);
    // fused post@lin f32
    float* Wf1   = (float*)alloc(320 * 64 * 4);
    float* bfo1  = (float*)alloc(64 * 4);
    float* Wf2   = (float*)alloc(320 * 64 * 4);
    float* bfo2  = (float*)alloc(64 * 4);
    // packed bf16 B-fragments
    u16* W0p     = (u16*)alloc(128 * 64 * 2);
    u16* pre1p   = (u16*)alloc(64 * 128 * 2);
    u16* pre2p   = (u16*)alloc(64 * 128 * 2);
    u16* wf1p    = (u16*)alloc(320 * 64 * 2);
    u16* wf2p    = (u16*)alloc(320 * 64 * 2);
    // activations (bf16)
    u16* hA      = (u16*)alloc((size_t)N * 64 * 2);
    u16* hB      = (u16*)alloc((size_t)N * 64 * 2);
    u16* PQ      = (u16*)alloc((size_t)N * 128 * 2);

    detect_zero_kernel<<<1 + (nb + 1023) / 1024, 1024, 0, stream>>>(
        (const u32*)d_in[0], flag, bcnt, nb);

    CvtTab t{};
    int ci = 0;
    auto add = [&](int di, float* dst, int nn) {
        t.src[ci] = d_in[di]; t.dst[ci] = dst; t.n[ci] = nn; ci++;
    };
    add(3, W0f, 128 * 64);  add(4, b0f, 64);
    add(5, pre1, 128 * 64); add(6, preb1, 64);
    add(7, post1, 320 * 64); add(8, postb1, 64);
    add(9, lin1, 64 * 64);  add(10, linb1, 64);
    add(11, pre2, 128 * 64); add(12, preb2, 64);
    add(13, post2, 320 * 64); add(14, postb2, 64);
    add(15, lin2, 64 * 64); add(16, linb2, 64);
    add(17, W2f, 64);       add(18, b2f_, 1);
    int total = 0;
    for (int i = 0; i < 16; ++i) total += t.n[i];
    t.total = total;
    convert_kernel<<<(total + 255) / 256, 256, 0, stream>>>(t, flag);

    fuse_w_kernel<<<dim3(80, 2), 256, 0, stream>>>(
        post1, postb1, lin1, linb1, post2, postb2, lin2, linb2,
        Wf1, bfo1, Wf2, bfo2);

    PackTab pt{};
    pt.src[0] = W0f;  pt.dst[0] = W0p;   pt.NC[0] = 64;  pt.sz[0] = 128 * 64; pt.mode[0] = 0;
    pt.src[1] = pre1; pt.dst[1] = pre1p; pt.NC[1] = 128; pt.sz[1] = 64 * 128; pt.mode[1] = 1;
    pt.src[2] = pre2; pt.dst[2] = pre2p; pt.NC[2] = 128; pt.sz[2] = 64 * 128; pt.mode[2] = 1;
    pt.src[3] = Wf1;  pt.dst[3] = wf1p;  pt.NC[3] = 64;  pt.sz[3] = 320 * 64; pt.mode[3] = 0;
    pt.src[4] = Wf2;  pt.dst[4] = wf2p;  pt.NC[4] = 64;  pt.sz[4] = 320 * 64; pt.mode[4] = 0;
    pt.total = pt.sz[0] + pt.sz[1] + pt.sz[2] + pt.sz[3] + pt.sz[4];
    pack_kernel<<<(pt.total + 255) / 256, 256, 0, stream>>>(pt);

    // CSR build (bucketed)
    bucket_scatter_kernel<<<(E + 255) / 256, 256, 0, stream>>>(esrc, edst, bcnt, bstage, E);
    bucket_scan_kernel<<<1, 1024, 0, stream>>>(bcnt, bbase, nb);
    bucket_build_kernel<<<nb, 256, 0, stream>>>(bstage, bcnt, bbase, rowptr, elist, nb, N);

    int gblocks = (N + 63) / 64;
    // h = lrelu(x @ W0 + b0)
    mfma_gemm_kernel<128, 64, 1, true><<<gblocks, 256, 0, stream>>>(
        d_in[0], W0p, b0f, hA, flag, N);

    // layer 1
    mfma_gemm_kernel<64, 128, 0, false><<<gblocks, 256, 0, stream>>>(
        hA, pre1p, nullptr, PQ, flag, N);
    agg_gemm_kernel<0><<<gblocks, 256, 0, stream>>>(
        PQ, hA, rowptr, elist, preb1, wf1p, bfo1, hB,
        nullptr, nullptr, nullptr, flag, N);

    // layer 2 (+ fused final h@W2+b2)
    mfma_gemm_kernel<64, 128, 0, false><<<gblocks, 256, 0, stream>>>(
        hB, pre2p, nullptr, PQ, flag, N);
    agg_gemm_kernel<1><<<gblocks, 256, 0, stream>>>(
        PQ, hB, rowptr, elist, preb2, wf2p, bfo2, nullptr,
        W2f, b2f_, d_out, flag, N);
}

// Round 5
// 249.644 us; speedup vs baseline: 2.4861x; 2.4861x over previous
//
#include <hip/hip_runtime.h>
#include <hip/hip_bf16.h>

typedef __hip_bfloat16 bf16;
typedef unsigned short u16;
typedef unsigned int u32;
typedef __attribute__((ext_vector_type(8))) short short8;
typedef __attribute__((ext_vector_type(4))) float f32x4;

static constexpr float AVG_LOG_C = 2.8332133440562162f; // ln(17)
#define BCAP 4096   // staging capacity per 128-node bucket (avg ~2046)
#define CHUNK 8192  // edges per scatter block

__device__ __forceinline__ u32 f2bf_bits(float f) {
    u32 u = __float_as_uint(f);
    return (u + 0x7fffu + ((u >> 16) & 1u)) >> 16;   // RNE to bf16 bits
}
__device__ __forceinline__ float bf2f(u16 b) {
    return __uint_as_float(((u32)b) << 16);
}

// ---------------------------------------------------------------- detect + zero bucket counters
__global__ __launch_bounds__(1024) void detect_zero_kernel(
    const u32* __restrict__ xwords, int* __restrict__ flag,
    int* __restrict__ bcnt, int nb) {
    if (blockIdx.x == 0) {
        int tid = threadIdx.x;
        if (tid < 64) {
            int good = 0;
            for (int i = tid; i < 2048; i += 64) {
                u32 lo = xwords[i] & 0xffffu;
                float v = __uint_as_float(lo << 16);
                float a = fabsf(v);
                if (v == 0.0f || (a >= 1e-3f && a <= 100.0f)) good++;
            }
            for (int off = 32; off; off >>= 1) good += __shfl_xor(good, off, 64);
            if (tid == 0) *flag = (2 * good > 2048) ? 1 : 0;
        }
    } else {
        int i = (blockIdx.x - 1) * 1024 + threadIdx.x;
        if (i < nb) bcnt[i] = 0;
    }
}

// ---------------------------------------------------------------- convert weights to f32 masters
struct CvtTab {
    const void* src[16];
    float* dst[16];
    int n[16];
    int total;
};

__global__ void convert_kernel(CvtTab t, const int* __restrict__ flag) {
    int i = blockIdx.x * 256 + threadIdx.x;
    if (i >= t.total) return;
    int k = 0;
    while (i >= t.n[k]) { i -= t.n[k]; ++k; }
    float v;
    if (*flag)
        v = __bfloat162float(((const bf16*)t.src[k])[i]);
    else
        v = ((const float*)t.src[k])[i];
    t.dst[k][i] = v;
}

// ---------------------------------------------------------------- bucketed CSR build
// pass 1: chunked reservation scatter — LDS histogram per 8192-edge chunk,
// ONE global atomic per (block,bucket), LDS-cursor scatter into reserved span.
__global__ __launch_bounds__(1024) void bucket_scatter_kernel(
    const int* __restrict__ srcs, const int* __restrict__ dsts,
    int* __restrict__ bcnt, u32* __restrict__ bstage, int e, int nb) {
    __shared__ int lhist[1024];
    __shared__ int lbase[1024];
    int tid = threadIdx.x;
    int cbase = blockIdx.x * CHUNK;
    for (int b = tid; b < nb; b += 1024) lhist[b] = 0;
    __syncthreads();
#pragma unroll
    for (int i = 0; i < CHUNK; i += 1024) {
        int e0 = cbase + i + tid;
        if (e0 < e) atomicAdd(&lhist[dsts[e0] >> 7], 1);
    }
    __syncthreads();
    for (int b = tid; b < nb; b += 1024) {
        int c = lhist[b];
        lbase[b] = c ? atomicAdd(&bcnt[b], c) : 0;
        lhist[b] = 0;   // becomes cursor
    }
    __syncthreads();
#pragma unroll
    for (int i = 0; i < CHUNK; i += 1024) {
        int e0 = cbase + i + tid;
        if (e0 < e) {
            int d = dsts[e0];
            int b = d >> 7;
            int pos = lbase[b] + atomicAdd(&lhist[b], 1);
            if (pos < BCAP)
                bstage[(size_t)b * BCAP + pos] = (u32)srcs[e0] | ((u32)(d & 127) << 17);
        }
    }
}

// pass 2a: exclusive scan of bucket sizes (nb <= 1024, single block)
__global__ __launch_bounds__(1024) void bucket_scan_kernel(
    const int* __restrict__ bcnt, int* __restrict__ bbase, int nb) {
    __shared__ int wsum[16];
    int tid = threadIdx.x, lane = tid & 63, wave = tid >> 6;
    int v = (tid < nb) ? min(bcnt[tid], BCAP) : 0;
    int s = v;
    for (int off = 1; off < 64; off <<= 1) {
        int t = __shfl_up(s, (unsigned)off, 64);
        if (lane >= off) s += t;
    }
    if (lane == 63) wsum[wave] = s;
    __syncthreads();
    if (wave == 0 && lane < 16) {
        int w = wsum[lane];
        for (int off = 1; off < 16; off <<= 1) {
            int t = __shfl_up(w, (unsigned)off, 64);
            if (lane >= off) w += t;
        }
        wsum[lane] = w;
    }
    __syncthreads();
    int incl = s + (wave ? wsum[wave - 1] : 0);
    if (tid < nb) bbase[tid] = incl - v;
    if (tid == nb - 1) bbase[nb] = incl;
}

// pass 2b: per-bucket local sort -> rowptr + elist
__global__ __launch_bounds__(256) void bucket_build_kernel(
    const u32* __restrict__ bstage, const int* __restrict__ bcnt,
    const int* __restrict__ bbase, int* __restrict__ rowptr,
    int* __restrict__ elist, int nb, int n) {
    __shared__ int hist[128];
    __shared__ int hoff[128];
    int b = blockIdx.x, tid = threadIdx.x;
    int cb = min(bcnt[b], BCAP);
    int base = bbase[b];
    if (tid < 128) hist[tid] = 0;
    __syncthreads();
    const u32* st = bstage + (size_t)b * BCAP;
    for (int i = tid; i < cb; i += 256) atomicAdd(&hist[st[i] >> 17], 1);
    __syncthreads();
    if (tid == 0) {
        int run = 0;
        for (int j = 0; j < 128; ++j) { hoff[j] = run; run += hist[j]; }
    }
    __syncthreads();
    if (tid < 128) {
        int node = b * 128 + tid;
        if (node < n) rowptr[node] = base + hoff[tid];
        hist[tid] = hoff[tid];   // becomes cursor
    }
    if (b == 0 && tid == 254) rowptr[n] = bbase[nb];
    __syncthreads();
    for (int i = tid; i < cb; i += 256) {
        u32 e = st[i];
        int pos = atomicAdd(&hist[e >> 17], 1);
        elist[base + pos] = (int)(e & 0x1ffffu);
    }
}

// ---------------------------------------------------------------- fuse postW@linW (f32 out)
__global__ void fuse_w_kernel(
    const float* __restrict__ postW1, const float* __restrict__ postb1,
    const float* __restrict__ linW1, const float* __restrict__ linb1,
    const float* __restrict__ postW2, const float* __restrict__ postb2,
    const float* __restrict__ linW2, const float* __restrict__ linb2,
    float* __restrict__ Wf1, float* __restrict__ bfo1,
    float* __restrict__ Wf2, float* __restrict__ bfo2) {
    const float* postW = blockIdx.y ? postW2 : postW1;
    const float* postb = blockIdx.y ? postb2 : postb1;
    const float* linW  = blockIdx.y ? linW2  : linW1;
    const float* linb  = blockIdx.y ? linb2  : linb1;
    float* Wf          = blockIdx.y ? Wf2 : Wf1;
    float* bfo         = blockIdx.y ? bfo2 : bfo1;

    int idx = blockIdx.x * 256 + threadIdx.x;
    if (idx < 320 * 64) {
        int p = idx >> 6, c = idx & 63;
        float a = 0.f;
        for (int k = 0; k < 64; ++k)
            a = fmaf(postW[p * 64 + k], linW[k * 64 + c], a);
        Wf[idx] = a;
    }
    if (idx < 64) {
        float a = linb[idx];
        for (int k = 0; k < 64; ++k) a = fmaf(postb[k], linW[k * 64 + idx], a);
        bfo[idx] = a;
    }
}

// ---------------------------------------------------------------- pack weights into MFMA B-fragment order
struct PackTab {
    const float* src[5];
    u16* dst[5];
    int NC[5];
    int sz[5];
    int mode[5];
    int total;
};

__global__ void pack_kernel(PackTab t) {
    int idx = blockIdx.x * 256 + threadIdx.x;
    if (idx >= t.total) return;
    int k = 0;
    while (idx >= t.sz[k]) { idx -= t.sz[k]; ++k; }
    int NC = t.NC[k];
    int nc16 = NC >> 4;
    int j = idx & 7, l = (idx >> 3) & 63;
    int tt = idx >> 9;
    int c = tt % nc16, s = tt / nc16;
    int kk = s * 32 + (l >> 4) * 8 + j;
    int col = c * 16 + (l & 15);
    float v;
    if (t.mode[k] == 0) {
        v = t.src[k][kk * NC + col];
    } else {
        v = (col < 64) ? t.src[k][kk * 64 + col]
                       : t.src[k][(64 + kk) * 64 + (col - 64)];
    }
    t.dst[k][idx] = (u16)f2bf_bits(v);
}

// ---------------------------------------------------------------- generic MFMA GEMM
// out[n,NCOL] = act(A[n,K] @ B[K,NCOL] + bias). FINAL=1: instead write
// d_out[row] = relu(.) @ W2 + b2 (requires NCOL=64).
template<int K, int NCOL, int ACT, bool XMODE, int FINAL>  // ACT 0=none 1=lrelu 2=relu
__global__ __launch_bounds__(256) void mfma_gemm_kernel(
    const void* __restrict__ Araw, const u16* __restrict__ Bfrag,
    const float* __restrict__ bias, u16* __restrict__ out,
    const float* __restrict__ W2, const float* __restrict__ b2,
    void* __restrict__ fout, const int* __restrict__ flag, int n) {
    constexpr int S = K / 32, C = NCOL / 16;
    int wave = __builtin_amdgcn_readfirstlane(threadIdx.x >> 6);
    int lane = threadIdx.x & 63;
    int rowbase = blockIdx.x * 64 + wave * 16;
    int arow = rowbase + (lane & 15);
    if (arow >= n) arow = n - 1;
    int koff = (lane >> 4) * 8;
    f32x4 acc[C];
#pragma unroll
    for (int c = 0; c < C; ++c) acc[c] = f32x4{0.f, 0.f, 0.f, 0.f};

    bool isbf = true;
    if constexpr (XMODE) isbf = (*flag != 0);

#pragma unroll
    for (int s = 0; s < S; ++s) {
        short8 a;
        if (isbf) {
            a = *(const short8*)((const u16*)Araw + (size_t)arow * K + s * 32 + koff);
        } else {
            const float* xf = (const float*)Araw + (size_t)arow * K + s * 32 + koff;
            f32x4 x0 = *(const f32x4*)xf;
            f32x4 x1 = *(const f32x4*)(xf + 4);
#pragma unroll
            for (int j = 0; j < 4; ++j) {
                a[j]     = (short)f2bf_bits(x0[j]);
                a[4 + j] = (short)f2bf_bits(x1[j]);
            }
        }
#pragma unroll
        for (int c = 0; c < C; ++c) {
            short8 b = *(const short8*)(Bfrag + ((size_t)(s * C + c) * 64 + lane) * 8);
            acc[c] = __builtin_amdgcn_mfma_f32_16x16x32_bf16(a, b, acc[c], 0, 0, 0);
        }
    }
    // C/D layout: col = lane&15, row = (lane>>4)*4 + reg
    int r0 = rowbase + (lane >> 4) * 4;
    if constexpr (!FINAL) {
#pragma unroll
        for (int c = 0; c < C; ++c) {
            int col = c * 16 + (lane & 15);
            float bv = (ACT == 0) ? 0.f : bias[col];
#pragma unroll
            for (int r = 0; r < 4; ++r) {
                int row = r0 + r;
                if (row < n) {
                    float v = acc[c][r] + bv;
                    if (ACT == 1) v = v > 0.f ? v : 0.2f * v;
                    if (ACT == 2) v = fmaxf(v, 0.f);
                    out[(size_t)row * NCOL + col] = (u16)f2bf_bits(v);
                }
            }
        }
    } else {
        float part[4] = {0.f, 0.f, 0.f, 0.f};
#pragma unroll
        for (int c = 0; c < C; ++c) {
            int col = c * 16 + (lane & 15);
            float bv = bias[col];
            float w2 = W2[col];
#pragma unroll
            for (int r = 0; r < 4; ++r)
                part[r] = fmaf(fmaxf(acc[c][r] + bv, 0.f), w2, part[r]);
        }
#pragma unroll
        for (int r = 0; r < 4; ++r) {
            float v = part[r];
            v += __shfl_xor(v, 1, 64);
            v += __shfl_xor(v, 2, 64);
            v += __shfl_xor(v, 4, 64);
            v += __shfl_xor(v, 8, 64);
            if ((lane & 15) == 0) {
                int row = r0 + r;
                if (row < n) {
                    float res = v + b2[0];
                    if (*flag) ((u16*)fout)[row] = (u16)f2bf_bits(res);
                    else       ((float*)fout)[row] = res;
                }
            }
        }
    }
}

// ---------------------------------------------------------------- aggregation (gather) -> v[N,320] bf16
__global__ __launch_bounds__(256) void agg_kernel(
    const u16* __restrict__ PQ, const u16* __restrict__ h,
    const int* __restrict__ rowptr, const int* __restrict__ elist,
    const float* __restrict__ preb, u16* __restrict__ v, int n) {
    int wave = __builtin_amdgcn_readfirstlane(threadIdx.x >> 6);
    int lane = threadIdx.x & 63;
    int node = blockIdx.x * 4 + wave;
    if (node >= n) return;
    int beg = rowptr[node], end = rowptr[node + 1];
    int cnt = end - beg;
    float s = 0.f, m = -3.4e38f;
    int e = beg;
    for (; e + 4 <= end; e += 4) {
        int s0 = elist[e], s1 = elist[e + 1], s2 = elist[e + 2], s3 = elist[e + 3];
        float q0 = bf2f(PQ[(size_t)s0 * 128 + 64 + lane]);
        float q1 = bf2f(PQ[(size_t)s1 * 128 + 64 + lane]);
        float q2 = bf2f(PQ[(size_t)s2 * 128 + 64 + lane]);
        float q3 = bf2f(PQ[(size_t)s3 * 128 + 64 + lane]);
        s += (q0 + q1) + (q2 + q3);
        m = fmaxf(fmaxf(m, fmaxf(q0, q1)), fmaxf(q2, q3));
    }
    for (; e < end; ++e) {
        float q = bf2f(PQ[(size_t)elist[e] * 128 + 64 + lane]);
        s += q;
        m = fmaxf(m, q);
    }
    float mean, mx, deg;
    if (cnt > 0) {
        deg = (float)cnt;
        float p = bf2f(PQ[(size_t)node * 128 + lane]) + preb[lane];
        mean = p + s / deg;
        mx = p + m;
    } else {
        deg = 1.f; mean = 0.f; mx = 0.f;
    }
    float att = AVG_LOG_C / logf(deg + 1.f);
    float lin = deg * (1.f / 16.f);
    size_t vb = (size_t)node * 320;
    v[vb + lane]       = h[(size_t)node * 64 + lane];
    v[vb + 64 + lane]  = (u16)f2bf_bits(att * mean);
    v[vb + 128 + lane] = (u16)f2bf_bits(att * mx);
    v[vb + 192 + lane] = (u16)f2bf_bits(lin * mean);
    v[vb + 256 + lane] = (u16)f2bf_bits(lin * mx);
}

// ---------------------------------------------------------------- launch
extern "C" void kernel_launch(void* const* d_in, const int* in_sizes, int n_in,
                              void* d_out, int out_size, void* d_ws, size_t ws_size,
                              hipStream_t stream) {
    const int N = in_sizes[0] / 128;
    const int E = in_sizes[2] / 2;
    const int nb = (N + 127) >> 7;
    const int* ei = (const int*)d_in[2];
    const int* esrc = ei;
    const int* edst = ei + E;

    char* w = (char*)d_ws;
    auto alloc = [&](size_t bytes) -> void* {
        void* p = (void*)w;
        w += (bytes + 255) & ~(size_t)255;
        return p;
    };
    int* flag    = (int*)alloc(4);
    int* bcnt    = (int*)alloc((size_t)nb * 4);
    int* bbase   = (int*)alloc((size_t)(nb + 1) * 4);
    u32* bstage  = (u32*)alloc((size_t)nb * BCAP * 4);
    int* rowptr  = (int*)alloc((size_t)(N + 1) * 4);
    int* elist   = (int*)alloc((size_t)E * 4);
    // f32 masters
    float* W0f   = (float*)alloc(128 * 64 * 4);
    float* b0f   = (float*)alloc(64 * 4);
    float* pre1  = (float*)alloc(128 * 64 * 4);
    float* preb1 = (float*)alloc(64 * 4);
    float* post1 = (float*)alloc(320 * 64 * 4);
    float* postb1= (float*)alloc(64 * 4);
    float* lin1  = (float*)alloc(64 * 64 * 4);
    float* linb1 = (float*)alloc(64 * 4);
    float* pre2  = (float*)alloc(128 * 64 * 4);
    float* preb2 = (float*)alloc(64 * 4);
    float* post2 = (float*)alloc(320 * 64 * 4);
    float* postb2= (float*)alloc(64 * 4);
    float* lin2  = (float*)alloc(64 * 64 * 4);
    float* linb2 = (float*)alloc(64 * 4);
    float* W2f   = (float*)alloc(64 * 4);
    float* b2f_  = (float*)alloc(4);
    // fused post@lin f32
    float* Wf1   = (float*)alloc(320 * 64 * 4);
    float* bfo1  = (float*)alloc(64 * 4);
    float* Wf2   = (float*)alloc(320 * 64 * 4);
    float* bfo2  = (float*)alloc(64 * 4);
    // packed bf16 B-fragments
    u16* W0p     = (u16*)alloc(128 * 64 * 2);
    u16* pre1p   = (u16*)alloc(64 * 128 * 2);
    u16* pre2p   = (u16*)alloc(64 * 128 * 2);
    u16* wf1p    = (u16*)alloc(320 * 64 * 2);
    u16* wf2p    = (u16*)alloc(320 * 64 * 2);
    // activations (bf16)
    u16* hA      = (u16*)alloc((size_t)N * 64 * 2);
    u16* hB      = (u16*)alloc((size_t)N * 64 * 2);
    u16* PQ      = (u16*)alloc((size_t)N * 128 * 2);
    u16* vbuf    = (u16*)alloc((size_t)N * 320 * 2);

    detect_zero_kernel<<<1 + (nb + 1023) / 1024, 1024, 0, stream>>>(
        (const u32*)d_in[0], flag, bcnt, nb);

    CvtTab t{};
    int ci = 0;
    auto add = [&](int di, float* dst, int nn) {
        t.src[ci] = d_in[di]; t.dst[ci] = dst; t.n[ci] = nn; ci++;
    };
    add(3, W0f, 128 * 64);  add(4, b0f, 64);
    add(5, pre1, 128 * 64); add(6, preb1, 64);
    add(7, post1, 320 * 64); add(8, postb1, 64);
    add(9, lin1, 64 * 64);  add(10, linb1, 64);
    add(11, pre2, 128 * 64); add(12, preb2, 64);
    add(13, post2, 320 * 64); add(14, postb2, 64);
    add(15, lin2, 64 * 64); add(16, linb2, 64);
    add(17, W2f, 64);       add(18, b2f_, 1);
    int total = 0;
    for (int i = 0; i < 16; ++i) total += t.n[i];
    t.total = total;
    convert_kernel<<<(total + 255) / 256, 256, 0, stream>>>(t, flag);

    fuse_w_kernel<<<dim3(80, 2), 256, 0, stream>>>(
        post1, postb1, lin1, linb1, post2, postb2, lin2, linb2,
        Wf1, bfo1, Wf2, bfo2);

    PackTab pt{};
    pt.src[0] = W0f;  pt.dst[0] = W0p;   pt.NC[0] = 64;  pt.sz[0] = 128 * 64; pt.mode[0] = 0;
    pt.src[1] = pre1; pt.dst[1] = pre1p; pt.NC[1] = 128; pt.sz[1] = 64 * 128; pt.mode[1] = 1;
    pt.src[2] = pre2; pt.dst[2] = pre2p; pt.NC[2] = 128; pt.sz[2] = 64 * 128; pt.mode[2] = 1;
    pt.src[3] = Wf1;  pt.dst[3] = wf1p;  pt.NC[3] = 64;  pt.sz[3] = 320 * 64; pt.mode[3] = 0;
    pt.src[4] = Wf2;  pt.dst[4] = wf2p;  pt.NC[4] = 64;  pt.sz[4] = 320 * 64; pt.mode[4] = 0;
    pt.total = pt.sz[0] + pt.sz[1] + pt.sz[2] + pt.sz[3] + pt.sz[4];
    pack_kernel<<<(pt.total + 255) / 256, 256, 0, stream>>>(pt);

    // CSR build (bucketed, chunked reservation)
    bucket_scatter_kernel<<<(E + CHUNK - 1) / CHUNK, 1024, 0, stream>>>(
        esrc, edst, bcnt, bstage, E, nb);
    bucket_scan_kernel<<<1, 1024, 0, stream>>>(bcnt, bbase, nb);
    bucket_build_kernel<<<nb, 256, 0, stream>>>(bstage, bcnt, bbase, rowptr, elist, nb, N);

    int gblocks = (N + 63) / 64;
    // h = lrelu(x @ W0 + b0)
    mfma_gemm_kernel<128, 64, 1, true, 0><<<gblocks, 256, 0, stream>>>(
        d_in[0], W0p, b0f, hA, nullptr, nullptr, nullptr, flag, N);

    // layer 1
    mfma_gemm_kernel<64, 128, 0, false, 0><<<gblocks, 256, 0, stream>>>(
        hA, pre1p, nullptr, PQ, nullptr, nullptr, nullptr, flag, N);
    agg_kernel<<<(N + 3) / 4, 256, 0, stream>>>(PQ, hA, rowptr, elist, preb1, vbuf, N);
    mfma_gemm_kernel<320, 64, 2, false, 0><<<gblocks, 256, 0, stream>>>(
        vbuf, wf1p, bfo1, hB, nullptr, nullptr, nullptr, flag, N);

    // layer 2 (+ fused final h@W2+b2 in the 320-GEMM epilogue)
    mfma_gemm_kernel<64, 128, 0, false, 0><<<gblocks, 256, 0, stream>>>(
        hB, pre2p, nullptr, PQ, nullptr, nullptr, nullptr, flag, N);
    agg_kernel<<<(N + 3) / 4, 256, 0, stream>>>(PQ, hB, rowptr, elist, preb2, vbuf, N);
    mfma_gemm_kernel<320, 64, 2, false, 1><<<gblocks, 256, 0, stream>>>(
        vbuf, wf2p, bfo2, nullptr, W2f, b2f_, d_out, flag, N);
}

// Round 7
// 224.169 us; speedup vs baseline: 2.7686x; 1.1136x over previous
//
#include <hip/hip_runtime.h>
#include <hip/hip_bf16.h>

typedef __hip_bfloat16 bf16;
typedef unsigned short u16;
typedef unsigned int u32;
typedef __attribute__((ext_vector_type(8))) short short8;
typedef __attribute__((ext_vector_type(4))) float f32x4;

static constexpr float AVG_LOG_C = 2.8332133440562162f; // ln(17)
#define BCAP 4096   // staging capacity per 128-node bucket (avg ~2046)
#define CHUNK 8192  // edges per scatter block

__device__ __forceinline__ u32 f2bf_bits(float f) {
    u32 u = __float_as_uint(f);
    return (u + 0x7fffu + ((u >> 16) & 1u)) >> 16;   // RNE to bf16 bits
}
__device__ __forceinline__ float bf2f(u16 b) {
    return __uint_as_float(((u32)b) << 16);
}

// ---------------------------------------------------------------- detect + zero bucket counters
__global__ __launch_bounds__(1024) void detect_zero_kernel(
    const u32* __restrict__ xwords, int* __restrict__ flag,
    int* __restrict__ bcnt, int nb) {
    if (blockIdx.x == 0) {
        int tid = threadIdx.x;
        if (tid < 64) {
            int good = 0;
            for (int i = tid; i < 2048; i += 64) {
                u32 lo = xwords[i] & 0xffffu;
                float v = __uint_as_float(lo << 16);
                float a = fabsf(v);
                if (v == 0.0f || (a >= 1e-3f && a <= 100.0f)) good++;
            }
            for (int off = 32; off; off >>= 1) good += __shfl_xor(good, off, 64);
            if (tid == 0) *flag = (2 * good > 2048) ? 1 : 0;
        }
    } else {
        int i = (blockIdx.x - 1) * 1024 + threadIdx.x;
        if (i < nb) bcnt[i] = 0;
    }
}

// ---------------------------------------------------------------- unified prep
__global__ void prep_kernel(
    const void* __restrict__ W0r,  const void* __restrict__ b0r,
    const void* __restrict__ pre1r, const void* __restrict__ preb1r,
    const void* __restrict__ post1r, const void* __restrict__ postb1r,
    const void* __restrict__ lin1r, const void* __restrict__ linb1r,
    const void* __restrict__ pre2r, const void* __restrict__ preb2r,
    const void* __restrict__ post2r, const void* __restrict__ postb2r,
    const void* __restrict__ lin2r, const void* __restrict__ linb2r,
    const void* __restrict__ W2r,  const void* __restrict__ b2r,
    u16* __restrict__ W0p, u16* __restrict__ pre1p, u16* __restrict__ pre2p,
    u16* __restrict__ wf1p, u16* __restrict__ wf2p,
    float* __restrict__ bfo1, float* __restrict__ bfo2,
    float* __restrict__ preb1f, float* __restrict__ preb2f,
    float* __restrict__ b0f, float* __restrict__ W2f, float* __restrict__ b2f,
    const int* __restrict__ flag) {
    int idx = blockIdx.x * 256 + threadIdx.x;
    bool isbf = (*flag) != 0;
    auto ld = [&](const void* p, int i) -> float {
        return isbf ? bf2f(((const u16*)p)[i]) : ((const float*)p)[i];
    };
    // --- W0p: pack mode0, K=128, NC=64 (nc16=4)
    if (idx < 8192) {
        int j = idx & 7, l = (idx >> 3) & 63, tt = idx >> 9;
        int c = tt & 3, s = tt >> 2;
        int kk = s * 32 + (l >> 4) * 8 + j;
        int col = c * 16 + (l & 15);
        W0p[idx] = (u16)f2bf_bits(ld(W0r, kk * 64 + col));
        return;
    }
    idx -= 8192;
    // --- pre1p/pre2p: pack mode1 (logical Wcat[64,128] from pre_W[128,64])
    for (int which = 0; which < 2; ++which) {
        if (idx < 8192) {
            const void* src = which ? pre2r : pre1r;
            u16* dst = which ? pre2p : pre1p;
            int j = idx & 7, l = (idx >> 3) & 63, tt = idx >> 9;
            int c = tt & 7, s = tt >> 3;
            int kk = s * 32 + (l >> 4) * 8 + j;
            int col = c * 16 + (l & 15);
            float v = (col < 64) ? ld(src, kk * 64 + col)
                                 : ld(src, (64 + kk) * 64 + (col - 64));
            dst[idx] = (u16)f2bf_bits(v);
            return;
        }
        idx -= 8192;
    }
    // --- wf1p/wf2p: fused (postW@linW)[kk,col], packed mode0, K=320, NC=64
    for (int which = 0; which < 2; ++which) {
        if (idx < 20480) {
            const void* postW = which ? post2r : post1r;
            const void* linW  = which ? lin2r  : lin1r;
            u16* dst = which ? wf2p : wf1p;
            int j = idx & 7, l = (idx >> 3) & 63, tt = idx >> 9;
            int c = tt & 3, s = tt >> 2;
            int kk = s * 32 + (l >> 4) * 8 + j;
            int col = c * 16 + (l & 15);
            float a = 0.f;
            for (int k = 0; k < 64; ++k)
                a = fmaf(ld(postW, kk * 64 + k), ld(linW, k * 64 + col), a);
            dst[idx] = (u16)f2bf_bits(a);
            return;
        }
        idx -= 20480;
    }
    // --- fused biases: bfo = linb + postb @ linW
    for (int which = 0; which < 2; ++which) {
        if (idx < 64) {
            const void* postb = which ? postb2r : postb1r;
            const void* linW  = which ? lin2r : lin1r;
            const void* linb  = which ? linb2r : linb1r;
            float* dst = which ? bfo2 : bfo1;
            float a = ld(linb, idx);
            for (int k = 0; k < 64; ++k)
                a = fmaf(ld(postb, k), ld(linW, k * 64 + idx), a);
            dst[idx] = a;
            return;
        }
        idx -= 64;
    }
    if (idx < 64) { preb1f[idx] = ld(preb1r, idx); return; }
    idx -= 64;
    if (idx < 64) { preb2f[idx] = ld(preb2r, idx); return; }
    idx -= 64;
    if (idx < 64) { b0f[idx] = ld(b0r, idx); return; }
    idx -= 64;
    if (idx < 64) { W2f[idx] = ld(W2r, idx); return; }
    idx -= 64;
    if (idx < 1) { b2f[0] = ld(b2r, 0); }
}
#define PREP_TOTAL (8192 * 3 + 20480 * 2 + 64 * 6 + 1)

// ---------------------------------------------------------------- bucketed CSR build
__global__ __launch_bounds__(1024) void bucket_scatter_kernel(
    const int* __restrict__ srcs, const int* __restrict__ dsts,
    int* __restrict__ bcnt, u32* __restrict__ bstage, int e, int nb) {
    __shared__ int lhist[1024];
    __shared__ int lbase[1024];
    int tid = threadIdx.x;
    int cbase = blockIdx.x * CHUNK;
    for (int b = tid; b < nb; b += 1024) lhist[b] = 0;
    __syncthreads();
#pragma unroll
    for (int i = 0; i < CHUNK; i += 1024) {
        int e0 = cbase + i + tid;
        if (e0 < e) atomicAdd(&lhist[dsts[e0] >> 7], 1);
    }
    __syncthreads();
    for (int b = tid; b < nb; b += 1024) {
        int c = lhist[b];
        lbase[b] = c ? atomicAdd(&bcnt[b], c) : 0;
        lhist[b] = 0;   // becomes cursor
    }
    __syncthreads();
#pragma unroll
    for (int i = 0; i < CHUNK; i += 1024) {
        int e0 = cbase + i + tid;
        if (e0 < e) {
            int d = dsts[e0];
            int b = d >> 7;
            int pos = lbase[b] + atomicAdd(&lhist[b], 1);
            if (pos < BCAP)
                bstage[(size_t)b * BCAP + pos] = (u32)srcs[e0] | ((u32)(d & 127) << 17);
        }
    }
}

__global__ __launch_bounds__(256) void bucket_build_kernel(
    const u32* __restrict__ bstage, const int* __restrict__ bcnt,
    int* __restrict__ rowptr, int* __restrict__ elist, int nb, int n) {
    __shared__ int hist[128];
    __shared__ int hoff[128];
    __shared__ int sbase;
    int b = blockIdx.x, tid = threadIdx.x;
    int lane = tid & 63;
    if (tid == 0) sbase = 0;
    if (tid < 128) hist[tid] = 0;
    __syncthreads();
    int part = 0;
    for (int k = tid; k < b; k += 256) part += min(bcnt[k], BCAP);
    for (int off = 32; off; off >>= 1) part += __shfl_xor(part, off, 64);
    if (lane == 0 && part) atomicAdd(&sbase, part);
    int cb = min(bcnt[b], BCAP);
    const u32* st = bstage + (size_t)b * BCAP;
    for (int i = tid; i < cb; i += 256) atomicAdd(&hist[st[i] >> 17], 1);
    __syncthreads();
    int base = sbase;
    if (tid == 0) {
        int run = 0;
        for (int j = 0; j < 128; ++j) { hoff[j] = run; run += hist[j]; }
    }
    __syncthreads();
    if (tid < 128) {
        int node = b * 128 + tid;
        if (node < n) rowptr[node] = base + hoff[tid];
        hist[tid] = hoff[tid];   // becomes cursor
    }
    if (b == nb - 1 && tid == 255) rowptr[n] = base + cb;
    __syncthreads();
    for (int i = tid; i < cb; i += 256) {
        u32 e = st[i];
        int pos = atomicAdd(&hist[e >> 17], 1);
        elist[base + pos] = (int)(e & 0x1ffffu);
    }
}

// ---------------------------------------------------------------- gemm_x + fused pq1
__global__ __launch_bounds__(1024) void gemm_x_pq_kernel(
    const void* __restrict__ xraw, const u16* __restrict__ W0p,
    const float* __restrict__ b0f, const u16* __restrict__ pre1p,
    u16* __restrict__ hA, u16* __restrict__ PQ,
    const int* __restrict__ flag, int n) {
    __shared__ __align__(16) u16 xsh[64 * 136];
    __shared__ __align__(16) u16 hsh[64 * 72];
    int tid = threadIdx.x;
    int wave = __builtin_amdgcn_readfirstlane(tid >> 6);
    int lane = tid & 63;
    int blockbase = blockIdx.x * 64;
    bool isbf = (*flag) != 0;
    // phase 0: stage x tile (64x128 bf16)
    {
        int row = tid >> 4;
        int cg = (tid & 15) * 8;
        int grow = blockbase + row;
        short8 v = short8{0, 0, 0, 0, 0, 0, 0, 0};
        if (grow < n) {
            if (isbf) {
                v = *(const short8*)((const u16*)xraw + (size_t)grow * 128 + cg);
            } else {
                const float* xf = (const float*)xraw + (size_t)grow * 128 + cg;
                f32x4 a0 = *(const f32x4*)xf;
                f32x4 a1 = *(const f32x4*)(xf + 4);
#pragma unroll
                for (int j = 0; j < 4; ++j) {
                    v[j]     = (short)f2bf_bits(a0[j]);
                    v[4 + j] = (short)f2bf_bits(a1[j]);
                }
            }
        }
        *(short8*)&xsh[row * 136 + cg] = v;
    }
    __syncthreads();
    // phase 1: h tile (wave -> one 16x16 tile), K=128 (S=4)
    int rt = wave & 3, ct = wave >> 2;
    int arl = rt * 16 + (lane & 15);
    int koff = (lane >> 4) * 8;
    f32x4 acc = f32x4{0.f, 0.f, 0.f, 0.f};
#pragma unroll
    for (int s = 0; s < 4; ++s) {
        short8 a = *(const short8*)&xsh[arl * 136 + s * 32 + koff];
        short8 b = *(const short8*)(W0p + ((size_t)(s * 4 + ct) * 64 + lane) * 8);
        acc = __builtin_amdgcn_mfma_f32_16x16x32_bf16(a, b, acc, 0, 0, 0);
    }
    {
        int col = ct * 16 + (lane & 15);
        float bv = b0f[col];
        int r0l = rt * 16 + (lane >> 4) * 4;
#pragma unroll
        for (int r = 0; r < 4; ++r) {
            float v = acc[r] + bv;
            v = v > 0.f ? v : 0.2f * v;
            u16 bits = (u16)f2bf_bits(v);
            hsh[(r0l + r) * 72 + col] = bits;
            int grow = blockbase + r0l + r;
            if (grow < n) hA[(size_t)grow * 64 + col] = bits;
        }
    }
    __syncthreads();
    // phase 2: PQ = h @ pre1 (K=64, NCOL=128): 32 tiles, 2 per wave
#pragma unroll
    for (int half = 0; half < 2; ++half) {
        int tile = wave * 2 + half;
        int rt2 = tile & 3, ct2 = tile >> 2;
        int ar2 = rt2 * 16 + (lane & 15);
        f32x4 acc2 = f32x4{0.f, 0.f, 0.f, 0.f};
#pragma unroll
        for (int s = 0; s < 2; ++s) {
            short8 a = *(const short8*)&hsh[ar2 * 72 + s * 32 + koff];
            short8 b = *(const short8*)(pre1p + ((size_t)(s * 8 + ct2) * 64 + lane) * 8);
            acc2 = __builtin_amdgcn_mfma_f32_16x16x32_bf16(a, b, acc2, 0, 0, 0);
        }
        int col2 = ct2 * 16 + (lane & 15);
        int r02 = rt2 * 16 + (lane >> 4) * 4;
#pragma unroll
        for (int r = 0; r < 4; ++r) {
            int grow = blockbase + r02 + r;
            if (grow < n) PQ[(size_t)grow * 128 + col2] = (u16)f2bf_bits(acc2[r]);
        }
    }
}

// ---------------------------------------------------------------- fused agg + 320-GEMM
// NOTE: PQin and PQout MUST be distinct buffers — the gather reads arbitrary
// rows of PQin while other blocks write PQout (cross-block race if aliased).
template<int FINAL>
__global__ __launch_bounds__(1024) void agg_gemm_kernel(
    const u16* __restrict__ PQ, const u16* __restrict__ h,
    const int* __restrict__ rowptr, const int* __restrict__ elist,
    const float* __restrict__ prebf, const u16* __restrict__ Wfp,
    const float* __restrict__ bfo, const u16* __restrict__ prenextp,
    u16* __restrict__ hout, u16* __restrict__ PQout,
    const float* __restrict__ W2f, const float* __restrict__ b2f,
    void* __restrict__ out, const int* __restrict__ flag, int n) {
    constexpr int PAD = 328;
    __shared__ __align__(16) u16 vsh[64 * PAD];   // 41 KB
    __shared__ __align__(16) u16 hsh[64 * 72];    // 9 KB (FINAL=0 path)
    __shared__ float fsum[64];
    int tid = threadIdx.x;
    int wave = __builtin_amdgcn_readfirstlane(tid >> 6);
    int lane = tid & 63;
    int blockbase = blockIdx.x * 64;
    float pbl = prebf[lane];
    if (FINAL && tid < 64) fsum[tid] = 0.f;
    // phase 0: gather (4 nodes per wave)
#pragma unroll
    for (int t = 0; t < 4; ++t) {
        int nl = wave * 4 + t;
        int node = blockbase + nl;
        u16* vrow = &vsh[nl * PAD];
        if (node < n) {
            int beg = rowptr[node], end = rowptr[node + 1];
            int cnt = end - beg;
            float s = 0.f, m = -3.4e38f;
            int e = beg;
            for (; e + 4 <= end; e += 4) {
                int s0 = elist[e], s1 = elist[e + 1], s2 = elist[e + 2], s3 = elist[e + 3];
                float q0 = bf2f(PQ[(size_t)s0 * 128 + 64 + lane]);
                float q1 = bf2f(PQ[(size_t)s1 * 128 + 64 + lane]);
                float q2 = bf2f(PQ[(size_t)s2 * 128 + 64 + lane]);
                float q3 = bf2f(PQ[(size_t)s3 * 128 + 64 + lane]);
                s += (q0 + q1) + (q2 + q3);
                m = fmaxf(fmaxf(m, fmaxf(q0, q1)), fmaxf(q2, q3));
            }
            for (; e < end; ++e) {
                float q = bf2f(PQ[(size_t)elist[e] * 128 + 64 + lane]);
                s += q;
                m = fmaxf(m, q);
            }
            float mean, mx, deg;
            if (cnt > 0) {
                deg = (float)cnt;
                float p = bf2f(PQ[(size_t)node * 128 + lane]) + pbl;
                mean = p + s / deg;
                mx = p + m;
            } else {
                deg = 1.f; mean = 0.f; mx = 0.f;
            }
            float att = AVG_LOG_C / logf(deg + 1.f);
            float lin = deg * (1.f / 16.f);
            vrow[lane]       = h[(size_t)node * 64 + lane];
            vrow[64 + lane]  = (u16)f2bf_bits(att * mean);
            vrow[128 + lane] = (u16)f2bf_bits(att * mx);
            vrow[192 + lane] = (u16)f2bf_bits(lin * mean);
            vrow[256 + lane] = (u16)f2bf_bits(lin * mx);
        } else {
            vrow[lane] = 0; vrow[64 + lane] = 0; vrow[128 + lane] = 0;
            vrow[192 + lane] = 0; vrow[256 + lane] = 0;
        }
    }
    __syncthreads();
    // phase 1: 320->64 GEMM, wave -> one 16x16 tile (S=10)
    int rt = wave & 3, ct = wave >> 2;
    int arl = rt * 16 + (lane & 15);
    int koff = (lane >> 4) * 8;
    f32x4 acc = f32x4{0.f, 0.f, 0.f, 0.f};
#pragma unroll
    for (int s = 0; s < 10; ++s) {
        short8 a = *(const short8*)&vsh[arl * PAD + s * 32 + koff];
        short8 b = *(const short8*)(Wfp + ((size_t)(s * 4 + ct) * 64 + lane) * 8);
        acc = __builtin_amdgcn_mfma_f32_16x16x32_bf16(a, b, acc, 0, 0, 0);
    }
    int col = ct * 16 + (lane & 15);
    float bv = bfo[col];
    int r0l = rt * 16 + (lane >> 4) * 4;
    if constexpr (!FINAL) {
#pragma unroll
        for (int r = 0; r < 4; ++r) {
            float v = fmaxf(acc[r] + bv, 0.f);
            u16 bits = (u16)f2bf_bits(v);
            hsh[(r0l + r) * 72 + col] = bits;
            int grow = blockbase + r0l + r;
            if (grow < n) hout[(size_t)grow * 64 + col] = bits;
        }
        __syncthreads();
        // phase 2: PQout = hout @ prenext (K=64, NCOL=128)
#pragma unroll
        for (int half = 0; half < 2; ++half) {
            int tile = wave * 2 + half;
            int rt2 = tile & 3, ct2 = tile >> 2;
            int ar2 = rt2 * 16 + (lane & 15);
            f32x4 acc2 = f32x4{0.f, 0.f, 0.f, 0.f};
#pragma unroll
            for (int s = 0; s < 2; ++s) {
                short8 a = *(const short8*)&hsh[ar2 * 72 + s * 32 + koff];
                short8 b = *(const short8*)(prenextp + ((size_t)(s * 8 + ct2) * 64 + lane) * 8);
                acc2 = __builtin_amdgcn_mfma_f32_16x16x32_bf16(a, b, acc2, 0, 0, 0);
            }
            int col2 = ct2 * 16 + (lane & 15);
            int r02 = rt2 * 16 + (lane >> 4) * 4;
#pragma unroll
            for (int r = 0; r < 4; ++r) {
                int grow = blockbase + r02 + r;
                if (grow < n) PQout[(size_t)grow * 128 + col2] = (u16)f2bf_bits(acc2[r]);
            }
        }
    } else {
        float w2 = W2f[col];
        float part[4];
#pragma unroll
        for (int r = 0; r < 4; ++r)
            part[r] = fmaxf(acc[r] + bv, 0.f) * w2;
#pragma unroll
        for (int r = 0; r < 4; ++r) {
            float v = part[r];
            v += __shfl_xor(v, 1, 64);
            v += __shfl_xor(v, 2, 64);
            v += __shfl_xor(v, 4, 64);
            v += __shfl_xor(v, 8, 64);
            if ((lane & 15) == 0) atomicAdd(&fsum[r0l + r], v);
        }
        __syncthreads();
        if (tid < 64) {
            int grow = blockbase + tid;
            if (grow < n) {
                float res = fsum[tid] + b2f[0];
                if (*flag) ((u16*)out)[grow] = (u16)f2bf_bits(res);
                else       ((float*)out)[grow] = res;
            }
        }
    }
}

// ---------------------------------------------------------------- launch
extern "C" void kernel_launch(void* const* d_in, const int* in_sizes, int n_in,
                              void* d_out, int out_size, void* d_ws, size_t ws_size,
                              hipStream_t stream) {
    const int N = in_sizes[0] / 128;
    const int E = in_sizes[2] / 2;
    const int nb = (N + 127) >> 7;
    const int* ei = (const int*)d_in[2];
    const int* esrc = ei;
    const int* edst = ei + E;

    char* w = (char*)d_ws;
    auto alloc = [&](size_t bytes) -> void* {
        void* p = (void*)w;
        w += (bytes + 255) & ~(size_t)255;
        return p;
    };
    int* flag    = (int*)alloc(4);
    int* bcnt    = (int*)alloc((size_t)nb * 4);
    u32* bstage  = (u32*)alloc((size_t)nb * BCAP * 4);
    int* rowptr  = (int*)alloc((size_t)(N + 1) * 4);
    int* elist   = (int*)alloc((size_t)E * 4);
    // packed bf16 B-fragments
    u16* W0p     = (u16*)alloc(128 * 64 * 2);
    u16* pre1p   = (u16*)alloc(64 * 128 * 2);
    u16* pre2p   = (u16*)alloc(64 * 128 * 2);
    u16* wf1p    = (u16*)alloc(320 * 64 * 2);
    u16* wf2p    = (u16*)alloc(320 * 64 * 2);
    // f32 bias vectors
    float* bfo1  = (float*)alloc(64 * 4);
    float* bfo2  = (float*)alloc(64 * 4);
    float* preb1f= (float*)alloc(64 * 4);
    float* preb2f= (float*)alloc(64 * 4);
    float* b0f   = (float*)alloc(64 * 4);
    float* W2f   = (float*)alloc(64 * 4);
    float* b2f_  = (float*)alloc(4);
    // activations (bf16) — PQA/PQB double-buffered (cross-block race if shared)
    u16* hA      = (u16*)alloc((size_t)N * 64 * 2);
    u16* hB      = (u16*)alloc((size_t)N * 64 * 2);
    u16* PQA     = (u16*)alloc((size_t)N * 128 * 2);
    u16* PQB     = (u16*)alloc((size_t)N * 128 * 2);

    detect_zero_kernel<<<1 + (nb + 1023) / 1024, 1024, 0, stream>>>(
        (const u32*)d_in[0], flag, bcnt, nb);

    prep_kernel<<<(PREP_TOTAL + 255) / 256, 256, 0, stream>>>(
        d_in[3], d_in[4], d_in[5], d_in[6], d_in[7], d_in[8], d_in[9], d_in[10],
        d_in[11], d_in[12], d_in[13], d_in[14], d_in[15], d_in[16], d_in[17], d_in[18],
        W0p, pre1p, pre2p, wf1p, wf2p,
        bfo1, bfo2, preb1f, preb2f, b0f, W2f, b2f_, flag);

    bucket_scatter_kernel<<<(E + CHUNK - 1) / CHUNK, 1024, 0, stream>>>(
        esrc, edst, bcnt, bstage, E, nb);
    bucket_build_kernel<<<nb, 256, 0, stream>>>(bstage, bcnt, rowptr, elist, nb, N);

    int gblocks = (N + 63) / 64;
    gemm_x_pq_kernel<<<gblocks, 1024, 0, stream>>>(
        d_in[0], W0p, b0f, pre1p, hA, PQA, flag, N);

    agg_gemm_kernel<0><<<gblocks, 1024, 0, stream>>>(
        PQA, hA, rowptr, elist, preb1f, wf1p, bfo1, pre2p, hB, PQB,
        nullptr, nullptr, nullptr, flag, N);

    agg_gemm_kernel<1><<<gblocks, 1024, 0, stream>>>(
        PQB, hB, rowptr, elist, preb2f, wf2p, bfo2, nullptr, nullptr, nullptr,
        W2f, b2f_, d_out, flag, N);
}

// Round 8
// 205.867 us; speedup vs baseline: 3.0148x; 1.0889x over previous
//
#include <hip/hip_runtime.h>
#include <hip/hip_bf16.h>

typedef __hip_bfloat16 bf16;
typedef unsigned short u16;
typedef unsigned int u32;
typedef __attribute__((ext_vector_type(8))) short short8;
typedef __attribute__((ext_vector_type(4))) float f32x4;

static constexpr float AVG_LOG_C = 2.8332133440562162f; // ln(17)
#define BCAP 2048   // staging capacity per 64-node bucket (avg ~1023)
#define CHUNK 8192  // edges per scatter block
#define PREP_TOTAL (8192 * 3 + 20480 * 2 + 64 * 6 + 1)

__device__ __forceinline__ u32 f2bf_bits(float f) {
    u32 u = __float_as_uint(f);
    return (u + 0x7fffu + ((u >> 16) & 1u)) >> 16;   // RNE to bf16 bits
}
__device__ __forceinline__ float bf2f(u16 b) {
    return __uint_as_float(((u32)b) << 16);
}

// ---------------------------------------------------------------- detect + zero bucket counters
__global__ __launch_bounds__(1024) void detect_zero_kernel(
    const u32* __restrict__ xwords, int* __restrict__ flag,
    int* __restrict__ bcnt, int nb) {
    if (blockIdx.x == 0) {
        int tid = threadIdx.x;
        if (tid < 64) {
            int good = 0;
            for (int i = tid; i < 2048; i += 64) {
                u32 lo = xwords[i] & 0xffffu;
                float v = __uint_as_float(lo << 16);
                float a = fabsf(v);
                if (v == 0.0f || (a >= 1e-3f && a <= 100.0f)) good++;
            }
            for (int off = 32; off; off >>= 1) good += __shfl_xor(good, off, 64);
            if (tid == 0) *flag = (2 * good > 2048) ? 1 : 0;
        }
    } else {
        int i = (blockIdx.x - 1) * 1024 + threadIdx.x;
        if (i < nb) bcnt[i] = 0;
    }
}

// ---------------------------------------------------------------- prep + bucket scatter (merged)
// blocks [0, scatB): chunked-reservation scatter into 64-node bucket staging.
// blocks [scatB, ...): weight packing / fusion / bias conversion.
__global__ __launch_bounds__(1024) void prep_scatter_kernel(
    const int* __restrict__ srcs, const int* __restrict__ dsts,
    int* __restrict__ bcnt, u32* __restrict__ bstage, int e, int nb,
    const void* __restrict__ W0r,  const void* __restrict__ b0r,
    const void* __restrict__ pre1r, const void* __restrict__ preb1r,
    const void* __restrict__ post1r, const void* __restrict__ postb1r,
    const void* __restrict__ lin1r, const void* __restrict__ linb1r,
    const void* __restrict__ pre2r, const void* __restrict__ preb2r,
    const void* __restrict__ post2r, const void* __restrict__ postb2r,
    const void* __restrict__ lin2r, const void* __restrict__ linb2r,
    const void* __restrict__ W2r,  const void* __restrict__ b2r,
    u16* __restrict__ W0p, u16* __restrict__ pre1p, u16* __restrict__ pre2p,
    u16* __restrict__ wf1p, u16* __restrict__ wf2p,
    float* __restrict__ bfo1, float* __restrict__ bfo2,
    float* __restrict__ preb1f, float* __restrict__ preb2f,
    float* __restrict__ b0f, float* __restrict__ W2f, float* __restrict__ b2f,
    const int* __restrict__ flag) {
    __shared__ int lhist[1024];
    __shared__ int lbase[1024];
    int tid = threadIdx.x;
    int scatB = (e + CHUNK - 1) / CHUNK;
    if ((int)blockIdx.x < scatB) {
        int cbase = blockIdx.x * CHUNK;
        for (int b = tid; b < nb; b += 1024) lhist[b] = 0;
        __syncthreads();
#pragma unroll
        for (int i = 0; i < CHUNK; i += 1024) {
            int e0 = cbase + i + tid;
            if (e0 < e) atomicAdd(&lhist[dsts[e0] >> 6], 1);
        }
        __syncthreads();
        for (int b = tid; b < nb; b += 1024) {
            int c = lhist[b];
            lbase[b] = c ? atomicAdd(&bcnt[b], c) : 0;
            lhist[b] = 0;   // becomes cursor
        }
        __syncthreads();
#pragma unroll
        for (int i = 0; i < CHUNK; i += 1024) {
            int e0 = cbase + i + tid;
            if (e0 < e) {
                int d = dsts[e0];
                int b = d >> 6;
                int pos = lbase[b] + atomicAdd(&lhist[b], 1);
                if (pos < BCAP)
                    bstage[(size_t)b * BCAP + pos] = (u32)srcs[e0] | ((u32)(d & 63) << 17);
            }
        }
        return;
    }
    // ------- prep portion -------
    int idx = ((int)blockIdx.x - scatB) * 1024 + tid;
    bool isbf = (*flag) != 0;
    auto ld = [&](const void* p, int i) -> float {
        return isbf ? bf2f(((const u16*)p)[i]) : ((const float*)p)[i];
    };
    if (idx < 8192) {   // W0p: mode0, K=128, NC=64
        int j = idx & 7, l = (idx >> 3) & 63, tt = idx >> 9;
        int c = tt & 3, s = tt >> 2;
        int kk = s * 32 + (l >> 4) * 8 + j;
        int col = c * 16 + (l & 15);
        W0p[idx] = (u16)f2bf_bits(ld(W0r, kk * 64 + col));
        return;
    }
    idx -= 8192;
    for (int which = 0; which < 2; ++which) {   // pre1p/pre2p: mode1
        if (idx < 8192) {
            const void* src = which ? pre2r : pre1r;
            u16* dst = which ? pre2p : pre1p;
            int j = idx & 7, l = (idx >> 3) & 63, tt = idx >> 9;
            int c = tt & 7, s = tt >> 3;
            int kk = s * 32 + (l >> 4) * 8 + j;
            int col = c * 16 + (l & 15);
            float v = (col < 64) ? ld(src, kk * 64 + col)
                                 : ld(src, (64 + kk) * 64 + (col - 64));
            dst[idx] = (u16)f2bf_bits(v);
            return;
        }
        idx -= 8192;
    }
    for (int which = 0; which < 2; ++which) {   // wf1p/wf2p: fused postW@linW
        if (idx < 20480) {
            const void* postW = which ? post2r : post1r;
            const void* linW  = which ? lin2r  : lin1r;
            u16* dst = which ? wf2p : wf1p;
            int j = idx & 7, l = (idx >> 3) & 63, tt = idx >> 9;
            int c = tt & 3, s = tt >> 2;
            int kk = s * 32 + (l >> 4) * 8 + j;
            int col = c * 16 + (l & 15);
            float a = 0.f;
            for (int k = 0; k < 64; ++k)
                a = fmaf(ld(postW, kk * 64 + k), ld(linW, k * 64 + col), a);
            dst[idx] = (u16)f2bf_bits(a);
            return;
        }
        idx -= 20480;
    }
    for (int which = 0; which < 2; ++which) {   // bfo = linb + postb @ linW
        if (idx < 64) {
            const void* postb = which ? postb2r : postb1r;
            const void* linW  = which ? lin2r : lin1r;
            const void* linb  = which ? linb2r : linb1r;
            float* dst = which ? bfo2 : bfo1;
            float a = ld(linb, idx);
            for (int k = 0; k < 64; ++k)
                a = fmaf(ld(postb, k), ld(linW, k * 64 + idx), a);
            dst[idx] = a;
            return;
        }
        idx -= 64;
    }
    if (idx < 64) { preb1f[idx] = ld(preb1r, idx); return; }
    idx -= 64;
    if (idx < 64) { preb2f[idx] = ld(preb2r, idx); return; }
    idx -= 64;
    if (idx < 64) { b0f[idx] = ld(b0r, idx); return; }
    idx -= 64;
    if (idx < 64) { W2f[idx] = ld(W2r, idx); return; }
    idx -= 64;
    if (idx < 1) { b2f[0] = ld(b2r, 0); }
}

// ---------------------------------------------------------------- gemm_x + fused pq1
__global__ __launch_bounds__(1024) void gemm_x_pq_kernel(
    const void* __restrict__ xraw, const u16* __restrict__ W0p,
    const float* __restrict__ b0f, const u16* __restrict__ pre1p,
    u16* __restrict__ hA, u16* __restrict__ PQ,
    const int* __restrict__ flag, int n) {
    __shared__ __align__(16) u16 xsh[64 * 136];
    __shared__ __align__(16) u16 hsh[64 * 72];
    int tid = threadIdx.x;
    int wave = __builtin_amdgcn_readfirstlane(tid >> 6);
    int lane = tid & 63;
    int blockbase = blockIdx.x * 64;
    bool isbf = (*flag) != 0;
    // phase 0: stage x tile (64x128 bf16)
    {
        int row = tid >> 4;
        int cg = (tid & 15) * 8;
        int grow = blockbase + row;
        short8 v = short8{0, 0, 0, 0, 0, 0, 0, 0};
        if (grow < n) {
            if (isbf) {
                v = *(const short8*)((const u16*)xraw + (size_t)grow * 128 + cg);
            } else {
                const float* xf = (const float*)xraw + (size_t)grow * 128 + cg;
                f32x4 a0 = *(const f32x4*)xf;
                f32x4 a1 = *(const f32x4*)(xf + 4);
#pragma unroll
                for (int j = 0; j < 4; ++j) {
                    v[j]     = (short)f2bf_bits(a0[j]);
                    v[4 + j] = (short)f2bf_bits(a1[j]);
                }
            }
        }
        *(short8*)&xsh[row * 136 + cg] = v;
    }
    __syncthreads();
    // phase 1: h tile (wave -> one 16x16 tile), K=128 (S=4)
    int rt = wave & 3, ct = wave >> 2;
    int arl = rt * 16 + (lane & 15);
    int koff = (lane >> 4) * 8;
    f32x4 acc = f32x4{0.f, 0.f, 0.f, 0.f};
#pragma unroll
    for (int s = 0; s < 4; ++s) {
        short8 a = *(const short8*)&xsh[arl * 136 + s * 32 + koff];
        short8 b = *(const short8*)(W0p + ((size_t)(s * 4 + ct) * 64 + lane) * 8);
        acc = __builtin_amdgcn_mfma_f32_16x16x32_bf16(a, b, acc, 0, 0, 0);
    }
    {
        int col = ct * 16 + (lane & 15);
        float bv = b0f[col];
        int r0l = rt * 16 + (lane >> 4) * 4;
#pragma unroll
        for (int r = 0; r < 4; ++r) {
            float v = acc[r] + bv;
            v = v > 0.f ? v : 0.2f * v;
            u16 bits = (u16)f2bf_bits(v);
            hsh[(r0l + r) * 72 + col] = bits;
            int grow = blockbase + r0l + r;
            if (grow < n) hA[(size_t)grow * 64 + col] = bits;
        }
    }
    __syncthreads();
    // phase 2: PQ = h @ pre1 (K=64, NCOL=128): 32 tiles, 2 per wave
#pragma unroll
    for (int half = 0; half < 2; ++half) {
        int tile = wave * 2 + half;
        int rt2 = tile & 3, ct2 = tile >> 2;
        int ar2 = rt2 * 16 + (lane & 15);
        f32x4 acc2 = f32x4{0.f, 0.f, 0.f, 0.f};
#pragma unroll
        for (int s = 0; s < 2; ++s) {
            short8 a = *(const short8*)&hsh[ar2 * 72 + s * 32 + koff];
            short8 b = *(const short8*)(pre1p + ((size_t)(s * 8 + ct2) * 64 + lane) * 8);
            acc2 = __builtin_amdgcn_mfma_f32_16x16x32_bf16(a, b, acc2, 0, 0, 0);
        }
        int col2 = ct2 * 16 + (lane & 15);
        int r02 = rt2 * 16 + (lane >> 4) * 4;
#pragma unroll
        for (int r = 0; r < 4; ++r) {
            int grow = blockbase + r02 + r;
            if (grow < n) PQ[(size_t)grow * 128 + col2] = (u16)f2bf_bits(acc2[r]);
        }
    }
}

// ---------------------------------------------------------------- fused local-CSR + agg + 320-GEMM
// block b <-> 64-node bucket b. Builds local CSR in LDS from bstage, gathers,
// then MFMA 320->64. PQin/PQout MUST be distinct buffers (cross-block race).
template<int FINAL>
__global__ __launch_bounds__(1024) void agg_gemm_kernel(
    const u16* __restrict__ PQ, const u16* __restrict__ h,
    const u32* __restrict__ bstage, const int* __restrict__ bcnt,
    const float* __restrict__ prebf, const u16* __restrict__ Wfp,
    const float* __restrict__ bfo, const u16* __restrict__ prenextp,
    u16* __restrict__ hout, u16* __restrict__ PQout,
    const float* __restrict__ W2f, const float* __restrict__ b2f,
    void* __restrict__ out, const int* __restrict__ flag, int n) {
    constexpr int PAD = 328;
    __shared__ __align__(16) u16 vsh[64 * PAD];   // 41 KB
    __shared__ __align__(16) u16 hsh[64 * 72];    // 9 KB
    __shared__ u32 lel[BCAP];                     // 8 KB local elist
    __shared__ int loff[64], lcnt[64], lcur[64];
    __shared__ float fsum[64];
    int tid = threadIdx.x;
    int wave = __builtin_amdgcn_readfirstlane(tid >> 6);
    int lane = tid & 63;
    int b = blockIdx.x;
    int blockbase = b * 64;
    float pbl = prebf[lane];
    if (tid < 64) { lcnt[tid] = 0; if (FINAL) fsum[tid] = 0.f; }
    __syncthreads();
    // phase 0a: local CSR from bucket staging
    int cb = min(bcnt[b], BCAP);
    const u32* st = bstage + (size_t)b * BCAP;
    for (int i = tid; i < cb; i += 1024) atomicAdd(&lcnt[st[i] >> 17], 1);
    __syncthreads();
    if (wave == 0) {
        int c = lcnt[lane];
        int s = c;
        for (int off = 1; off < 64; off <<= 1) {
            int t = __shfl_up(s, (unsigned)off, 64);
            if (lane >= off) s += t;
        }
        loff[lane] = s - c;
        lcur[lane] = s - c;
    }
    __syncthreads();
    for (int i = tid; i < cb; i += 1024) {
        u32 e = st[i];
        int pos = atomicAdd(&lcur[e >> 17], 1);
        lel[pos] = e & 0x1ffffu;
    }
    __syncthreads();
    // phase 0b: gather (4 nodes per wave)
    const u16* Qb = PQ + 64 + lane;
#pragma unroll
    for (int t = 0; t < 4; ++t) {
        int nl = wave * 4 + t;
        int node = blockbase + nl;
        u16* vrow = &vsh[nl * PAD];
        if (node < n) {
            int beg = loff[nl], end = beg + lcnt[nl];
            int cnt = end - beg;
            float s = 0.f, m = -3.4e38f;
            int e = beg;
            for (; e + 8 <= end; e += 8) {
                float q0 = bf2f(Qb[(size_t)lel[e] * 128]);
                float q1 = bf2f(Qb[(size_t)lel[e + 1] * 128]);
                float q2 = bf2f(Qb[(size_t)lel[e + 2] * 128]);
                float q3 = bf2f(Qb[(size_t)lel[e + 3] * 128]);
                float q4 = bf2f(Qb[(size_t)lel[e + 4] * 128]);
                float q5 = bf2f(Qb[(size_t)lel[e + 5] * 128]);
                float q6 = bf2f(Qb[(size_t)lel[e + 6] * 128]);
                float q7 = bf2f(Qb[(size_t)lel[e + 7] * 128]);
                s += ((q0 + q1) + (q2 + q3)) + ((q4 + q5) + (q6 + q7));
                m = fmaxf(m, fmaxf(fmaxf(fmaxf(q0, q1), fmaxf(q2, q3)),
                                   fmaxf(fmaxf(q4, q5), fmaxf(q6, q7))));
            }
            for (; e + 4 <= end; e += 4) {
                float q0 = bf2f(Qb[(size_t)lel[e] * 128]);
                float q1 = bf2f(Qb[(size_t)lel[e + 1] * 128]);
                float q2 = bf2f(Qb[(size_t)lel[e + 2] * 128]);
                float q3 = bf2f(Qb[(size_t)lel[e + 3] * 128]);
                s += (q0 + q1) + (q2 + q3);
                m = fmaxf(fmaxf(m, fmaxf(q0, q1)), fmaxf(q2, q3));
            }
            for (; e < end; ++e) {
                float q = bf2f(Qb[(size_t)lel[e] * 128]);
                s += q;
                m = fmaxf(m, q);
            }
            float mean, mx, deg;
            if (cnt > 0) {
                deg = (float)cnt;
                float p = bf2f(PQ[(size_t)node * 128 + lane]) + pbl;
                mean = p + s / deg;
                mx = p + m;
            } else {
                deg = 1.f; mean = 0.f; mx = 0.f;
            }
            float att = AVG_LOG_C / logf(deg + 1.f);
            float lin = deg * (1.f / 16.f);
            vrow[lane]       = h[(size_t)node * 64 + lane];
            vrow[64 + lane]  = (u16)f2bf_bits(att * mean);
            vrow[128 + lane] = (u16)f2bf_bits(att * mx);
            vrow[192 + lane] = (u16)f2bf_bits(lin * mean);
            vrow[256 + lane] = (u16)f2bf_bits(lin * mx);
        } else {
            vrow[lane] = 0; vrow[64 + lane] = 0; vrow[128 + lane] = 0;
            vrow[192 + lane] = 0; vrow[256 + lane] = 0;
        }
    }
    __syncthreads();
    // phase 1: 320->64 GEMM, wave -> one 16x16 tile (S=10)
    int rt = wave & 3, ct = wave >> 2;
    int arl = rt * 16 + (lane & 15);
    int koff = (lane >> 4) * 8;
    f32x4 acc = f32x4{0.f, 0.f, 0.f, 0.f};
#pragma unroll
    for (int s = 0; s < 10; ++s) {
        short8 a = *(const short8*)&vsh[arl * PAD + s * 32 + koff];
        short8 b2 = *(const short8*)(Wfp + ((size_t)(s * 4 + ct) * 64 + lane) * 8);
        acc = __builtin_amdgcn_mfma_f32_16x16x32_bf16(a, b2, acc, 0, 0, 0);
    }
    int col = ct * 16 + (lane & 15);
    float bv = bfo[col];
    int r0l = rt * 16 + (lane >> 4) * 4;
    if constexpr (!FINAL) {
#pragma unroll
        for (int r = 0; r < 4; ++r) {
            float v = fmaxf(acc[r] + bv, 0.f);
            u16 bits = (u16)f2bf_bits(v);
            hsh[(r0l + r) * 72 + col] = bits;
            int grow = blockbase + r0l + r;
            if (grow < n) hout[(size_t)grow * 64 + col] = bits;
        }
        __syncthreads();
        // phase 2: PQout = hout @ prenext (K=64, NCOL=128)
#pragma unroll
        for (int half = 0; half < 2; ++half) {
            int tile = wave * 2 + half;
            int rt2 = tile & 3, ct2 = tile >> 2;
            int ar2 = rt2 * 16 + (lane & 15);
            f32x4 acc2 = f32x4{0.f, 0.f, 0.f, 0.f};
#pragma unroll
            for (int s = 0; s < 2; ++s) {
                short8 a = *(const short8*)&hsh[ar2 * 72 + s * 32 + koff];
                short8 b2 = *(const short8*)(prenextp + ((size_t)(s * 8 + ct2) * 64 + lane) * 8);
                acc2 = __builtin_amdgcn_mfma_f32_16x16x32_bf16(a, b2, acc2, 0, 0, 0);
            }
            int col2 = ct2 * 16 + (lane & 15);
            int r02 = rt2 * 16 + (lane >> 4) * 4;
#pragma unroll
            for (int r = 0; r < 4; ++r) {
                int grow = blockbase + r02 + r;
                if (grow < n) PQout[(size_t)grow * 128 + col2] = (u16)f2bf_bits(acc2[r]);
            }
        }
    } else {
        float w2 = W2f[col];
        float part[4];
#pragma unroll
        for (int r = 0; r < 4; ++r)
            part[r] = fmaxf(acc[r] + bv, 0.f) * w2;
#pragma unroll
        for (int r = 0; r < 4; ++r) {
            float v = part[r];
            v += __shfl_xor(v, 1, 64);
            v += __shfl_xor(v, 2, 64);
            v += __shfl_xor(v, 4, 64);
            v += __shfl_xor(v, 8, 64);
            if ((lane & 15) == 0) atomicAdd(&fsum[r0l + r], v);
        }
        __syncthreads();
        if (tid < 64) {
            int grow = blockbase + tid;
            if (grow < n) {
                float res = fsum[tid] + b2f[0];
                if (*flag) ((u16*)out)[grow] = (u16)f2bf_bits(res);
                else       ((float*)out)[grow] = res;
            }
        }
    }
}

// ---------------------------------------------------------------- launch
extern "C" void kernel_launch(void* const* d_in, const int* in_sizes, int n_in,
                              void* d_out, int out_size, void* d_ws, size_t ws_size,
                              hipStream_t stream) {
    const int N = in_sizes[0] / 128;
    const int E = in_sizes[2] / 2;
    const int nb = (N + 63) >> 6;
    const int* ei = (const int*)d_in[2];
    const int* esrc = ei;
    const int* edst = ei + E;

    char* w = (char*)d_ws;
    auto alloc = [&](size_t bytes) -> void* {
        void* p = (void*)w;
        w += (bytes + 255) & ~(size_t)255;
        return p;
    };
    int* flag    = (int*)alloc(4);
    int* bcnt    = (int*)alloc((size_t)nb * 4);
    u32* bstage  = (u32*)alloc((size_t)nb * BCAP * 4);
    // packed bf16 B-fragments
    u16* W0p     = (u16*)alloc(128 * 64 * 2);
    u16* pre1p   = (u16*)alloc(64 * 128 * 2);
    u16* pre2p   = (u16*)alloc(64 * 128 * 2);
    u16* wf1p    = (u16*)alloc(320 * 64 * 2);
    u16* wf2p    = (u16*)alloc(320 * 64 * 2);
    // f32 bias vectors
    float* bfo1  = (float*)alloc(64 * 4);
    float* bfo2  = (float*)alloc(64 * 4);
    float* preb1f= (float*)alloc(64 * 4);
    float* preb2f= (float*)alloc(64 * 4);
    float* b0f   = (float*)alloc(64 * 4);
    float* W2f   = (float*)alloc(64 * 4);
    float* b2f_  = (float*)alloc(4);
    // activations (bf16) — PQA/PQB double-buffered (cross-block race if shared)
    u16* hA      = (u16*)alloc((size_t)N * 64 * 2);
    u16* hB      = (u16*)alloc((size_t)N * 64 * 2);
    u16* PQA     = (u16*)alloc((size_t)N * 128 * 2);
    u16* PQB     = (u16*)alloc((size_t)N * 128 * 2);

    detect_zero_kernel<<<1 + (nb + 1023) / 1024, 1024, 0, stream>>>(
        (const u32*)d_in[0], flag, bcnt, nb);

    int scatB = (E + CHUNK - 1) / CHUNK;
    int prepB = (PREP_TOTAL + 1023) / 1024;
    prep_scatter_kernel<<<scatB + prepB, 1024, 0, stream>>>(
        esrc, edst, bcnt, bstage, E, nb,
        d_in[3], d_in[4], d_in[5], d_in[6], d_in[7], d_in[8], d_in[9], d_in[10],
        d_in[11], d_in[12], d_in[13], d_in[14], d_in[15], d_in[16], d_in[17], d_in[18],
        W0p, pre1p, pre2p, wf1p, wf2p,
        bfo1, bfo2, preb1f, preb2f, b0f, W2f, b2f_, flag);

    int gblocks = (N + 63) / 64;
    gemm_x_pq_kernel<<<gblocks, 1024, 0, stream>>>(
        d_in[0], W0p, b0f, pre1p, hA, PQA, flag, N);

    agg_gemm_kernel<0><<<gblocks, 1024, 0, stream>>>(
        PQA, hA, bstage, bcnt, preb1f, wf1p, bfo1, pre2p, hB, PQB,
        nullptr, nullptr, nullptr, flag, N);

    agg_gemm_kernel<1><<<gblocks, 1024, 0, stream>>>(
        PQB, hB, bstage, bcnt, preb2f, wf2p, bfo2, nullptr, nullptr, nullptr,
        W2f, b2f_, d_out, flag, N);
}